// Round 4
// baseline (704.238 us; speedup 1.0000x reference)
//
#include <hip/hip_runtime.h>
#include <hip/hip_bf16.h>
#include <hip/hip_fp16.h>

// Problem constants
#define BATCH 4
#define SEQ   2048
#define HID   1024
#define HEADS 16
#define HDIM  64
#define MROWS (BATCH * SEQ)   // 8192
#define LOG2E 1.4426950408889634f
#define SCL   (LOG2E / 8.0f)  // log2e / sqrt(HDIM)

typedef _Float16 v8h __attribute__((ext_vector_type(8)));
typedef _Float16 v4h __attribute__((ext_vector_type(4)));
typedef _Float16 v2h __attribute__((ext_vector_type(2)));
typedef float    v4f __attribute__((ext_vector_type(4)));
typedef int      v4i __attribute__((ext_vector_type(4)));

#define MFMA16(a, b, c) __builtin_amdgcn_mfma_f32_16x16x32_f16((a), (b), (c), 0, 0, 0)

#if __has_builtin(__builtin_amdgcn_fdot2)
#define HAVE_FDOT2 1
#else
#define HAVE_FDOT2 0
#endif

__device__ inline int pk2(float a, float b) {
    return __builtin_bit_cast(int, __builtin_amdgcn_cvt_pkrtz(a, b));
}

// async global->LDS, 16B per lane; dest = wave-uniform base + lane*16
__device__ __forceinline__ void async16(const void* g, void* l) {
    __builtin_amdgcn_global_load_lds(
        (const __attribute__((address_space(1))) unsigned int*)g,
        (__attribute__((address_space(3))) unsigned int*)l, 16, 0, 0);
}

// swizzled LDS element offset for a 64-elem (128B) row: 16B chunk ^= row&7
#define SWZ(row, chunk) (((row) * 64) + ((((chunk) ^ ((row) & 7))) * 8))

// ---------------- prep: x f32 -> f16 ----------------
__global__ __launch_bounds__(256) void cvt_x(const float* __restrict__ x,
                                             _Float16* __restrict__ xb) {
    int i = blockIdx.x * 256 + threadIdx.x;     // one thread = 8 elems
    const float4* xp = (const float4*)x;
    float4 a = xp[2 * i];
    float4 b = xp[2 * i + 1];
    v4i o;
    o[0] = pk2(a.x, a.y); o[1] = pk2(a.z, a.w);
    o[2] = pk2(b.x, b.y); o[3] = pk2(b.z, b.w);
    ((v4i*)xb)[i] = o;
}

// ---------------- prep: W [K][N] f32 -> Wt [N][K] f16 ----------------
__global__ __launch_bounds__(256) void transw(const float* __restrict__ W,
                                              _Float16* __restrict__ Wt) {
    __shared__ float t[32][33];
    int bx = blockIdx.x * 32, by = blockIdx.y * 32;
    int tx = threadIdx.x, ty = threadIdx.y;     // (32, 8)
#pragma unroll
    for (int i = 0; i < 4; i++)
        t[ty + i * 8][tx] = W[(size_t)(by + ty + i * 8) * HID + bx + tx];
    __syncthreads();
#pragma unroll
    for (int i = 0; i < 4; i++)
        Wt[(size_t)(bx + ty + i * 8) * HID + by + tx] = (_Float16)t[tx][ty + i * 8];
}

// ---------------- prep: permuted bias (MFMA S^T fragment order, f16) ----
// biasT[b][K16][Q16][lane][r] = mask ? -|a|*log2e*t : -57344
// where k = K16*16 + (lane>>4)*4 + r, q = Q16*16 + (lane&15)
__global__ __launch_bounds__(256) void mkbias(const float* __restrict__ tiv,
                                              const int* __restrict__ msk,
                                              const float* __restrict__ alphap,
                                              _Float16* __restrict__ biasT) {
    __shared__ _Float16 L[16 * 264];
    const int b = blockIdx.z, Q16 = blockIdx.y, kc0 = blockIdx.x * 256;
    const int tid = threadIdx.x;
    const float ca = -fabsf(alphap[0]) * LOG2E;
    const int prow = tid >> 6;          // 0..3
    const int pcol = (tid & 63) * 4;    // 0..252
#pragma unroll
    for (int pi = 0; pi < 4; pi++) {
        int r = pi * 4 + prow;
        size_t g = ((size_t)b * SEQ + Q16 * 16 + r) * SEQ + kc0 + pcol;
        float4 tv = *(const float4*)(tiv + g);
        int4   mv = *(const int4*)(msk + g);
        float f0 = mv.x ? ca * tv.x : -57344.0f;
        float f1 = mv.y ? ca * tv.y : -57344.0f;
        float f2 = mv.z ? ca * tv.z : -57344.0f;
        float f3 = mv.w ? ca * tv.w : -57344.0f;
        int2 o; o.x = pk2(f0, f1); o.y = pk2(f2, f3);
        *(int2*)&L[r * 264 + pcol] = o;
    }
    __syncthreads();
    const int lane = tid & 63, tq = tid >> 6;
#pragma unroll
    for (int it = 0; it < 4; it++) {
        int K16i = it * 4 + tq;
        int kl = K16i * 16 + (lane >> 4) * 4;
        int qr = lane & 15;
        int2 v = *(const int2*)&L[qr * 264 + kl];
        size_t o = ((((size_t)b * 128 + (kc0 >> 4) + K16i) * 128 + Q16) * 64 + lane) * 4;
        *(int2*)&biasT[o] = v;
    }
}

// ---------------- QKV projection GEMM (f16, async swizzled staging) -----
__global__ __launch_bounds__(256) void gemm_qkv(
    const _Float16* __restrict__ xb, const _Float16* __restrict__ wt,
    const float* __restrict__ bq, const float* __restrict__ bk,
    const float* __restrict__ bv,
    _Float16* __restrict__ Qb, _Float16* __restrict__ Kb, _Float16* __restrict__ Vtb) {
    const int mode = blockIdx.z;
    const _Float16* w = wt + (size_t)mode * HID * HID;
    __shared__ _Float16 As[128 * 64];
    __shared__ _Float16 Bs[128 * 64];
    const int tid = threadIdx.x;
    const int wv = tid >> 6, lane = tid & 63;
    const int quad = lane >> 4, l15 = lane & 15;
    const int wr = wv >> 1, wc = wv & 1;
    const int m0 = blockIdx.y * 128;
    const int n0 = blockIdx.x * 128;

    v4f acc[4][4];
#pragma unroll
    for (int i = 0; i < 4; i++)
#pragma unroll
        for (int j = 0; j < 4; j++) acc[i][j] = (v4f){0.f, 0.f, 0.f, 0.f};

    const int srow = lane >> 3;         // 0..7 within 8-row chunk
    const int schk = lane & 7;          // 16B chunk within row
    const _Float16* Ag = xb + (size_t)m0 * HID;
    const _Float16* Bg = w + (size_t)n0 * HID;

    for (int k0 = 0; k0 < HID; k0 += 64) {
        __syncthreads();
#pragma unroll
        for (int i = 0; i < 4; i++) {
            int ra = wv * 32 + i * 8 + srow;            // 0..127
            int ca = schk ^ (ra & 7);
            async16(Ag + (size_t)ra * HID + k0 + ca * 8, &As[(wv * 32 + i * 8) * 64]);
            async16(Bg + (size_t)ra * HID + k0 + ca * 8, &Bs[(wv * 32 + i * 8) * 64]);
        }
        __syncthreads();
#pragma unroll
        for (int kc = 0; kc < 2; kc++) {
            v8h af[4], bf[4];
#pragma unroll
            for (int t = 0; t < 4; t++) {
                af[t] = *(const v8h*)&As[SWZ(wr * 64 + t * 16 + l15, kc * 4 + quad)];
                bf[t] = *(const v8h*)&Bs[SWZ(wc * 64 + t * 16 + l15, kc * 4 + quad)];
            }
#pragma unroll
            for (int tm = 0; tm < 4; tm++)
#pragma unroll
                for (int tn = 0; tn < 4; tn++)
                    acc[tm][tn] = MFMA16(af[tm], bf[tn], acc[tm][tn]);
        }
    }

    const float* pb = (mode == 0) ? bq : (mode == 1 ? bk : bv);
    const float oscl = (mode == 0) ? SCL : 1.0f;   // fold log2e/8 into Q
#pragma unroll
    for (int tm = 0; tm < 4; tm++) {
#pragma unroll
        for (int tn = 0; tn < 4; tn++) {
            int n = n0 + wc * 64 + tn * 16 + l15;
            float bval = pb[n];
            int h = n >> 6, d = n & 63;
#pragma unroll
            for (int r = 0; r < 4; r++) {
                int m = m0 + wr * 64 + tm * 16 + quad * 4 + r;
                int b = m >> 11, s = m & 2047;
                _Float16 hv = (_Float16)((acc[tm][tn][r] + bval) * oscl);
                if (mode == 2) {
                    Vtb[(((size_t)(b * HEADS + h) * HDIM + d) * SEQ) + s] = hv;
                } else {
                    _Float16* dst = (mode == 0) ? Qb : Kb;
                    dst[((size_t)(b * HEADS + h) * SEQ + s) * HDIM + d] = hv;
                }
            }
        }
    }
}

// ---------------- flash attention (S^T, barrier-free, global frags) -----
// grid (16 q-tiles, 64 b*h); block 256 (4 independent waves); wave = 32 q.
// K and V^T fragments are loaded straight from global in MFMA operand
// order (16B/lane, 64B segments, L2-hot). Only P round-trips through
// per-wave LDS (double-buffered by kt parity; XOR-swizzled, 2-way free).
__global__ __launch_bounds__(256, 4) void attn(
    const _Float16* __restrict__ Qb, const _Float16* __restrict__ Kb,
    const _Float16* __restrict__ Vtb, const _Float16* __restrict__ biasT,
    float* __restrict__ out) {
    const int bh = blockIdx.y;
    const int b = bh >> 4, h = bh & 15;
    const int qt = blockIdx.x;
    const int tid = threadIdx.x;
    const int wv = tid >> 6, lane = tid & 63;
    const int quad = lane >> 4, l15 = lane & 15;

    __shared__ _Float16 Ps[4][2][32 * 64];   // per-wave P[q][key], swizzled

    const int q0 = qt * 128 + wv * 32;
    const int Q16a = q0 >> 4;             // + tm

    const _Float16* Qp = Qb + (size_t)(b * HEADS + h) * SEQ * HDIM;
    const _Float16* Kp = Kb + (size_t)(b * HEADS + h) * SEQ * HDIM;
    const _Float16* Vp = Vtb + (size_t)(b * HEADS + h) * HDIM * SEQ;
    const _Float16* Bbase = biasT + (size_t)b * 128 * 128 * 64 * 4;

    // Q fragments (B-operand: lane l15 = qrow, k = d); Q is pre-scaled by SCL
    v8h qf[2][2];
#pragma unroll
    for (int tm = 0; tm < 2; tm++)
#pragma unroll
        for (int kc = 0; kc < 2; kc++)
            qf[tm][kc] = *(const v8h*)&Qp[(size_t)(q0 + tm * 16 + l15) * HDIM + kc * 32 + quad * 8];

    v4f oacc[2][4];
#pragma unroll
    for (int i = 0; i < 2; i++)
#pragma unroll
        for (int j = 0; j < 4; j++) oacc[i][j] = (v4f){0.f, 0.f, 0.f, 0.f};
    float lsum[2] = {0.f, 0.f};
#if HAVE_FDOT2
    const v2h one2 = {(_Float16)1.0f, (_Float16)1.0f};
#endif

#pragma unroll 2
    for (int kt = 0; kt < SEQ / 64; kt++) {
        const int key0 = kt * 64;
        _Float16* Pw = (_Float16*)Ps[wv][kt & 1];

        // bias fragments -> accumulator init (f16 pre-multiplied by log2e)
        v4f sacc[4][2];
#pragma unroll
        for (int nt = 0; nt < 4; nt++)
#pragma unroll
            for (int tm = 0; tm < 2; tm++) {
                int2 bl = *(const int2*)&Bbase[((((size_t)(key0 >> 4) + nt) * 128 + Q16a + tm) * 64 + lane) * 4];
                v4h bv = __builtin_bit_cast(v4h, bl);
                sacc[nt][tm] = (v4f){(float)bv[0], (float)bv[1], (float)bv[2], (float)bv[3]};
            }

        // S^T = K Q^T + bias : A-frag of K straight from global
        // (m = key = nt*16+l15, k = d = kc*32+quad*8+j)
#pragma unroll
        for (int kc = 0; kc < 2; kc++) {
            v8h kfr[4];
#pragma unroll
            for (int nt = 0; nt < 4; nt++)
                kfr[nt] = *(const v8h*)&Kp[(size_t)(key0 + nt * 16 + l15) * HDIM + kc * 32 + quad * 8];
#pragma unroll
            for (int nt = 0; nt < 4; nt++)
#pragma unroll
                for (int tm = 0; tm < 2; tm++)
                    sacc[nt][tm] = MFMA16(kfr[nt], qf[tm][kc], sacc[nt][tm]);
        }

        // V^T fragments from global, issued early so latency hides under exp
        // (n = d = nt*16+l15, k = key = kc*32+quad*8+j)
        v8h vfr[2][4];
#pragma unroll
        for (int kc = 0; kc < 2; kc++)
#pragma unroll
            for (int nt = 0; nt < 4; nt++)
                vfr[kc][nt] = *(const v8h*)&Vp[(size_t)(nt * 16 + l15) * SEQ + key0 + kc * 32 + quad * 8];

        // p = exp2(sacc); per-lane partial row sums; P -> per-wave LDS
#pragma unroll
        for (int nt = 0; nt < 4; nt++)
#pragma unroll
            for (int tm = 0; tm < 2; tm++) {
                float p0 = __builtin_amdgcn_exp2f(sacc[nt][tm][0]);
                float p1 = __builtin_amdgcn_exp2f(sacc[nt][tm][1]);
                float p2 = __builtin_amdgcn_exp2f(sacc[nt][tm][2]);
                float p3 = __builtin_amdgcn_exp2f(sacc[nt][tm][3]);
                int2 pkv;
                pkv.x = pk2(p0, p1);
                pkv.y = pk2(p2, p3);
#if HAVE_FDOT2
                lsum[tm] = __builtin_amdgcn_fdot2(__builtin_bit_cast(v2h, pkv.x), one2, lsum[tm], false);
                lsum[tm] = __builtin_amdgcn_fdot2(__builtin_bit_cast(v2h, pkv.y), one2, lsum[tm], false);
#else
                lsum[tm] += (p0 + p1) + (p2 + p3);
#endif
                // write 4 consecutive keys (8B) at row q, swizzled chunk
                int q = tm * 16 + l15;
                int c16 = nt * 2 + (quad >> 1), half = quad & 1;
                *(int2*)&Pw[q * 64 + ((c16 ^ (q & 7)) * 8) + half * 4] = pkv;
            }

        // O += P V  (A-frag of P from per-wave LDS; B-frag of V in regs)
#pragma unroll
        for (int kc = 0; kc < 2; kc++) {
            v8h pf[2];
#pragma unroll
            for (int tm = 0; tm < 2; tm++)
                pf[tm] = *(const v8h*)&Pw[SWZ(tm * 16 + l15, kc * 4 + quad)];
#pragma unroll
            for (int tm = 0; tm < 2; tm++)
#pragma unroll
                for (int nt = 0; nt < 4; nt++)
                    oacc[tm][nt] = MFMA16(pf[tm], vfr[kc][nt], oacc[tm][nt]);
        }
    }

    // epilogue: reduce row sums across quads, fetch per-C/D-row inverse, store
#pragma unroll
    for (int tm = 0; tm < 2; tm++) {
        float lt = lsum[tm];
        lt += __shfl_xor(lt, 16);
        lt += __shfl_xor(lt, 32);
        float inv[4];
#pragma unroll
        for (int r = 0; r < 4; r++)
            inv[r] = 1.0f / __shfl(lt, quad * 4 + r);
#pragma unroll
        for (int nt = 0; nt < 4; nt++)
#pragma unroll
            for (int r = 0; r < 4; r++) {
                int q = q0 + tm * 16 + quad * 4 + r;
                int d = nt * 16 + l15;
                out[((size_t)b * SEQ + q) * HID + h * HDIM + d] = oacc[tm][nt][r] * inv[r];
            }
    }
}

// ---------------- launch ----------------
extern "C" void kernel_launch(void* const* d_in, const int* in_sizes, int n_in,
                              void* d_out, int out_size, void* d_ws, size_t ws_size,
                              hipStream_t stream) {
    const float* x    = (const float*)d_in[0];
    const float* tiv  = (const float*)d_in[1];
    const int*   msk  = (const int*)d_in[2];
    const float* Wq   = (const float*)d_in[3];
    const float* bq   = (const float*)d_in[4];
    const float* Wk   = (const float*)d_in[5];
    const float* bk   = (const float*)d_in[6];
    const float* Wv   = (const float*)d_in[7];
    const float* bv   = (const float*)d_in[8];
    const float* alp  = (const float*)d_in[9];

    char* ws = (char*)d_ws;
    const size_t XB_OFF = 0;                                  // 16,777,216 B
    const size_t WT_OFF = XB_OFF + (size_t)MROWS * HID * 2;   // + 6,291,456 B
    const size_t Q_OFF  = WT_OFF + (size_t)3 * HID * HID * 2;
    const size_t K_OFF  = Q_OFF + (size_t)MROWS * HID * 2;
    const size_t V_OFF  = K_OFF + (size_t)MROWS * HID * 2;
    const size_t B_OFF  = V_OFF + (size_t)MROWS * HID * 2;    // biasT: 33,554,432 B

    _Float16* xb   = (_Float16*)(ws + XB_OFF);
    _Float16* wt   = (_Float16*)(ws + WT_OFF);
    _Float16* Qb   = (_Float16*)(ws + Q_OFF);
    _Float16* Kb   = (_Float16*)(ws + K_OFF);
    _Float16* Vtb  = (_Float16*)(ws + V_OFF);
    _Float16* bias = (_Float16*)(ws + B_OFF);

    cvt_x<<<MROWS * HID / (256 * 8), 256, 0, stream>>>(x, xb);
    dim3 tb(32, 8);
    transw<<<dim3(32, 32), tb, 0, stream>>>(Wq, wt);
    transw<<<dim3(32, 32), tb, 0, stream>>>(Wk, wt + HID * HID);
    transw<<<dim3(32, 32), tb, 0, stream>>>(Wv, wt + 2 * HID * HID);
    mkbias<<<dim3(SEQ / 256, SEQ / 16, BATCH), 256, 0, stream>>>(tiv, msk, alp, bias);
    gemm_qkv<<<dim3(HID / 128, MROWS / 128, 3), 256, 0, stream>>>(
        xb, wt, bq, bk, bv, Qb, Kb, Vtb);
    attn<<<dim3(SEQ / 128, BATCH * HEADS), 256, 0, stream>>>(Qb, Kb, Vtb, bias,
                                                             (float*)d_out);
}

// Round 6
// 392.674 us; speedup vs baseline: 1.7934x; 1.7934x over previous
//
#include <hip/hip_runtime.h>
#include <hip/hip_bf16.h>
#include <hip/hip_fp16.h>

// Problem constants
#define BATCH 4
#define SEQ   2048
#define HID   1024
#define HEADS 16
#define HDIM  64
#define MROWS (BATCH * SEQ)   // 8192
#define LOG2E 1.4426950408889634f
#define SCL   (LOG2E / 8.0f)  // log2e / sqrt(HDIM)

typedef _Float16 v8h __attribute__((ext_vector_type(8)));
typedef _Float16 v4h __attribute__((ext_vector_type(4)));
typedef _Float16 v2h __attribute__((ext_vector_type(2)));
typedef float    v4f __attribute__((ext_vector_type(4)));
typedef int      v4i __attribute__((ext_vector_type(4)));

#define MFMA16(a, b, c) __builtin_amdgcn_mfma_f32_16x16x32_f16((a), (b), (c), 0, 0, 0)
// 16x16x16 f16 MFMA (legacy gfx908 naming, still present on gfx950):
// A-frag layout (m=lane&15, k=quad*4+j) == S^T C/D layout, so exp(S^T)
// packs directly into PV A-fragments with NO LDS round-trip.
#define MFMA16K16(a, b, c) __builtin_amdgcn_mfma_f32_16x16x16f16((a), (b), (c), 0, 0, 0)

__device__ inline int pk2(float a, float b) {
    return __builtin_bit_cast(int, __builtin_amdgcn_cvt_pkrtz(a, b));
}

// async global->LDS, 16B per lane; dest = wave-uniform base + lane*16
__device__ __forceinline__ void async16(const void* g, void* l) {
    __builtin_amdgcn_global_load_lds(
        (const __attribute__((address_space(1))) unsigned int*)g,
        (__attribute__((address_space(3))) unsigned int*)l, 16, 0, 0);
}

// swizzled LDS element offset for a 64-elem (128B) row: 16B chunk ^= row&7
#define SWZ(row, chunk) (((row) * 64) + ((((chunk) ^ ((row) & 7))) * 8))

// ---------------- prep: x f32 -> f16 ----------------
__global__ __launch_bounds__(256) void cvt_x(const float* __restrict__ x,
                                             _Float16* __restrict__ xb) {
    int i = blockIdx.x * 256 + threadIdx.x;     // one thread = 8 elems
    const float4* xp = (const float4*)x;
    float4 a = xp[2 * i];
    float4 b = xp[2 * i + 1];
    v4i o;
    o[0] = pk2(a.x, a.y); o[1] = pk2(a.z, a.w);
    o[2] = pk2(b.x, b.y); o[3] = pk2(b.z, b.w);
    ((v4i*)xb)[i] = o;
}

// ---------------- prep: W [K][N] f32 -> Wt [N][K] f16 (3 mats, grid.z) ---
__global__ __launch_bounds__(256) void transw(const float* __restrict__ W0,
                                              const float* __restrict__ W1,
                                              const float* __restrict__ W2,
                                              _Float16* __restrict__ Wt) {
    const float* W = (blockIdx.z == 0) ? W0 : (blockIdx.z == 1 ? W1 : W2);
    _Float16* dst = Wt + (size_t)blockIdx.z * HID * HID;
    __shared__ float t[32][33];
    int bx = blockIdx.x * 32, by = blockIdx.y * 32;
    int tx = threadIdx.x, ty = threadIdx.y;     // (32, 8)
#pragma unroll
    for (int i = 0; i < 4; i++)
        t[ty + i * 8][tx] = W[(size_t)(by + ty + i * 8) * HID + bx + tx];
    __syncthreads();
#pragma unroll
    for (int i = 0; i < 4; i++)
        dst[(size_t)(bx + ty + i * 8) * HID + by + tx] = (_Float16)t[tx][ty + i * 8];
}

// ---------------- prep: permuted bias (MFMA S^T fragment order, f16) ----
// biasT[b][K16][Q16][lane][r] = mask ? -|a|*log2e*t : -57344
// where k = K16*16 + (lane>>4)*4 + r, q = Q16*16 + (lane&15)
__global__ __launch_bounds__(256) void mkbias(const float* __restrict__ tiv,
                                              const int* __restrict__ msk,
                                              const float* __restrict__ alphap,
                                              _Float16* __restrict__ biasT) {
    __shared__ _Float16 L[16 * 264];
    const int b = blockIdx.z, Q16 = blockIdx.y, kc0 = blockIdx.x * 256;
    const int tid = threadIdx.x;
    const float ca = -fabsf(alphap[0]) * LOG2E;
    const int prow = tid >> 6;          // 0..3
    const int pcol = (tid & 63) * 4;    // 0..252
#pragma unroll
    for (int pi = 0; pi < 4; pi++) {
        int r = pi * 4 + prow;
        size_t g = ((size_t)b * SEQ + Q16 * 16 + r) * SEQ + kc0 + pcol;
        float4 tv = *(const float4*)(tiv + g);
        int4   mv = *(const int4*)(msk + g);
        float f0 = mv.x ? ca * tv.x : -57344.0f;
        float f1 = mv.y ? ca * tv.y : -57344.0f;
        float f2 = mv.z ? ca * tv.z : -57344.0f;
        float f3 = mv.w ? ca * tv.w : -57344.0f;
        int2 o; o.x = pk2(f0, f1); o.y = pk2(f2, f3);
        *(int2*)&L[r * 264 + pcol] = o;
    }
    __syncthreads();
    const int lane = tid & 63, tq = tid >> 6;
#pragma unroll
    for (int it = 0; it < 4; it++) {
        int K16i = it * 4 + tq;
        int kl = K16i * 16 + (lane >> 4) * 4;
        int qr = lane & 15;
        int2 v = *(const int2*)&L[qr * 264 + kl];
        size_t o = ((((size_t)b * 128 + (kc0 >> 4) + K16i) * 128 + Q16) * 64 + lane) * 4;
        *(int2*)&biasT[o] = v;
    }
}

// ---------------- QKV projection GEMM (f16, async swizzled staging) -----
__global__ __launch_bounds__(256) void gemm_qkv(
    const _Float16* __restrict__ xb, const _Float16* __restrict__ wt,
    const float* __restrict__ bq, const float* __restrict__ bk,
    const float* __restrict__ bv,
    _Float16* __restrict__ Qb, _Float16* __restrict__ Kb, _Float16* __restrict__ Vtb) {
    const int mode = blockIdx.z;
    const _Float16* w = wt + (size_t)mode * HID * HID;
    __shared__ _Float16 As[128 * 64];
    __shared__ _Float16 Bs[128 * 64];
    const int tid = threadIdx.x;
    const int wv = tid >> 6, lane = tid & 63;
    const int quad = lane >> 4, l15 = lane & 15;
    const int wr = wv >> 1, wc = wv & 1;
    const int m0 = blockIdx.y * 128;
    const int n0 = blockIdx.x * 128;

    v4f acc[4][4];
#pragma unroll
    for (int i = 0; i < 4; i++)
#pragma unroll
        for (int j = 0; j < 4; j++) acc[i][j] = (v4f){0.f, 0.f, 0.f, 0.f};

    const int srow = lane >> 3;         // 0..7 within 8-row chunk
    const int schk = lane & 7;          // 16B chunk within row
    const _Float16* Ag = xb + (size_t)m0 * HID;
    const _Float16* Bg = w + (size_t)n0 * HID;

    for (int k0 = 0; k0 < HID; k0 += 64) {
        __syncthreads();
#pragma unroll
        for (int i = 0; i < 4; i++) {
            int ra = wv * 32 + i * 8 + srow;            // 0..127
            int ca = schk ^ (ra & 7);
            async16(Ag + (size_t)ra * HID + k0 + ca * 8, &As[(wv * 32 + i * 8) * 64]);
            async16(Bg + (size_t)ra * HID + k0 + ca * 8, &Bs[(wv * 32 + i * 8) * 64]);
        }
        __syncthreads();
#pragma unroll
        for (int kc = 0; kc < 2; kc++) {
            v8h af[4], bf[4];
#pragma unroll
            for (int t = 0; t < 4; t++) {
                af[t] = *(const v8h*)&As[SWZ(wr * 64 + t * 16 + l15, kc * 4 + quad)];
                bf[t] = *(const v8h*)&Bs[SWZ(wc * 64 + t * 16 + l15, kc * 4 + quad)];
            }
#pragma unroll
            for (int tm = 0; tm < 4; tm++)
#pragma unroll
                for (int tn = 0; tn < 4; tn++)
                    acc[tm][tn] = MFMA16(af[tm], bf[tn], acc[tm][tn]);
        }
    }

    const float* pb = (mode == 0) ? bq : (mode == 1 ? bk : bv);
    const float oscl = (mode == 0) ? SCL : 1.0f;   // fold log2e/8 into Q
#pragma unroll
    for (int tm = 0; tm < 4; tm++) {
#pragma unroll
        for (int tn = 0; tn < 4; tn++) {
            int n = n0 + wc * 64 + tn * 16 + l15;
            float bval = pb[n];
            int h = n >> 6, d = n & 63;
#pragma unroll
            for (int r = 0; r < 4; r++) {
                int m = m0 + wr * 64 + tm * 16 + quad * 4 + r;
                int b = m >> 11, s = m & 2047;
                _Float16 hv = (_Float16)((acc[tm][tn][r] + bval) * oscl);
                if (mode == 2) {
                    Vtb[(((size_t)(b * HEADS + h) * HDIM + d) * SEQ) + s] = hv;
                } else {
                    _Float16* dst = (mode == 0) ? Qb : Kb;
                    dst[((size_t)(b * HEADS + h) * SEQ + s) * HDIM + d] = hv;
                }
            }
        }
    }
}

// ---------------- flash attention (S^T, P stays in registers) -----------
// grid (16 q-tiles, 64 b*h); block 256 (4 waves); wave owns 32 q-rows.
// QK^T uses 16x16x32; PV uses 16x16x16 whose A-frag layout equals the
// S^T C/D layout, so P = exp(S^T) feeds PV directly from registers.
__global__ __launch_bounds__(256, 4) void attn(
    const _Float16* __restrict__ Qb, const _Float16* __restrict__ Kb,
    const _Float16* __restrict__ Vtb, const _Float16* __restrict__ biasT,
    float* __restrict__ out) {
    const int bh = blockIdx.y;
    const int b = bh >> 4, h = bh & 15;
    const int qt = blockIdx.x;
    const int tid = threadIdx.x;
    const int wv = tid >> 6, lane = tid & 63;
    const int quad = lane >> 4, l15 = lane & 15;

    __shared__ _Float16 Ks[64 * 64];      // [key][d], swizzled
    __shared__ _Float16 Vs[64 * 64];      // [d][key], swizzled

    const int q0 = qt * 128 + wv * 32;
    const int Q16a = q0 >> 4;             // + tm

    const _Float16* Qp = Qb + (size_t)(b * HEADS + h) * SEQ * HDIM;
    const _Float16* Kp = Kb + (size_t)(b * HEADS + h) * SEQ * HDIM;
    const _Float16* Vp = Vtb + (size_t)(b * HEADS + h) * HDIM * SEQ;
    const _Float16* Bbase = biasT + (size_t)b * 128 * 128 * 64 * 4;

    // Q fragments (B-operand: lane l15 = qrow, k = d); Q is pre-scaled by SCL
    v8h qf[2][2];
#pragma unroll
    for (int tm = 0; tm < 2; tm++)
#pragma unroll
        for (int kc = 0; kc < 2; kc++)
            qf[tm][kc] = *(const v8h*)&Qp[(size_t)(q0 + tm * 16 + l15) * HDIM + kc * 32 + quad * 8];

    v4f oacc[2][4];
#pragma unroll
    for (int i = 0; i < 2; i++)
#pragma unroll
        for (int j = 0; j < 4; j++) oacc[i][j] = (v4f){0.f, 0.f, 0.f, 0.f};
    float lsum[2] = {0.f, 0.f};

    const int srow = lane >> 3, schk = lane & 7;

    for (int kt = 0; kt < SEQ / 64; kt++) {
        const int key0 = kt * 64;
        // bias fragments -> accumulator init (f16 pre-multiplied by log2e)
        v4f sacc[4][2];
#pragma unroll
        for (int nt = 0; nt < 4; nt++)
#pragma unroll
            for (int tm = 0; tm < 2; tm++) {
                int2 bl = *(const int2*)&Bbase[((((size_t)(key0 >> 4) + nt) * 128 + Q16a + tm) * 64 + lane) * 4];
                v4h bv = __builtin_bit_cast(v4h, bl);
                sacc[nt][tm] = (v4f){(float)bv[0], (float)bv[1], (float)bv[2], (float)bv[3]};
            }

        __syncthreads();
        // stage K tile and V^T tile via async 16B, XOR-swizzled
#pragma unroll
        for (int i = 0; i < 2; i++) {
            int r = wv * 16 + i * 8 + srow;             // 0..63
            int c = schk ^ (r & 7);
            async16(Kp + (size_t)(key0 + r) * HDIM + c * 8, &Ks[(wv * 16 + i * 8) * 64]);
            async16(Vp + (size_t)r * SEQ + key0 + c * 8, &Vs[(wv * 16 + i * 8) * 64]);
        }
        __syncthreads();

        // S^T = K Q^T + bias : C/D row = key (quad*4+r), col = qrow (l15)
#pragma unroll
        for (int kc = 0; kc < 2; kc++) {
            v8h kfr[4];
#pragma unroll
            for (int nt = 0; nt < 4; nt++)
                kfr[nt] = *(const v8h*)&Ks[SWZ(nt * 16 + l15, kc * 4 + quad)];
#pragma unroll
            for (int nt = 0; nt < 4; nt++)
#pragma unroll
                for (int tm = 0; tm < 2; tm++)
                    sacc[nt][tm] = MFMA16(kfr[nt], qf[tm][kc], sacc[nt][tm]);
        }

        // p = exp2(sacc); pack pairs -> PV A-fragments (in registers!)
        int2 pfr[4][2];   // [key-16-tile][tm]: 4 f16, k = quad*4 + j
#pragma unroll
        for (int nt = 0; nt < 4; nt++)
#pragma unroll
            for (int tm = 0; tm < 2; tm++) {
                float p0 = __builtin_amdgcn_exp2f(sacc[nt][tm][0]);
                float p1 = __builtin_amdgcn_exp2f(sacc[nt][tm][1]);
                float p2 = __builtin_amdgcn_exp2f(sacc[nt][tm][2]);
                float p3 = __builtin_amdgcn_exp2f(sacc[nt][tm][3]);
                int2 pkv;
                pkv.x = pk2(p0, p1);
                pkv.y = pk2(p2, p3);
                lsum[tm] += (p0 + p1) + (p2 + p3);
                pfr[nt][tm] = pkv;
            }

        // O += P V via 16x16x16: A = pfr (regs), B = V^T b64 frags from LDS
        // (B-frag: lane l15 = d, k = g*16 + quad*4 + j)
#pragma unroll
        for (int g = 0; g < 4; g++) {
            v4h vfr[4];
#pragma unroll
            for (int nt = 0; nt < 4; nt++) {
                int row = nt * 16 + l15;                       // d
                int cc = g * 2 + (quad >> 1);                  // 16B chunk
                vfr[nt] = *(const v4h*)&Vs[row * 64 + ((cc ^ (row & 7)) * 8) + (quad & 1) * 4];
            }
#pragma unroll
            for (int tm = 0; tm < 2; tm++) {
                v4h pa = __builtin_bit_cast(v4h, pfr[g][tm]);
#pragma unroll
                for (int nt = 0; nt < 4; nt++)
                    oacc[tm][nt] = MFMA16K16(pa, vfr[nt], oacc[tm][nt]);
            }
        }
    }

    // epilogue: reduce row sums across quads, fetch per-C/D-row inverse, store
#pragma unroll
    for (int tm = 0; tm < 2; tm++) {
        float lt = lsum[tm];
        lt += __shfl_xor(lt, 16);
        lt += __shfl_xor(lt, 32);
        float inv[4];
#pragma unroll
        for (int r = 0; r < 4; r++)
            inv[r] = 1.0f / __shfl(lt, quad * 4 + r);
#pragma unroll
        for (int nt = 0; nt < 4; nt++)
#pragma unroll
            for (int r = 0; r < 4; r++) {
                int q = q0 + tm * 16 + quad * 4 + r;
                int d = nt * 16 + l15;
                out[((size_t)b * SEQ + q) * HID + h * HDIM + d] = oacc[tm][nt][r] * inv[r];
            }
    }
}

// ---------------- launch ----------------
extern "C" void kernel_launch(void* const* d_in, const int* in_sizes, int n_in,
                              void* d_out, int out_size, void* d_ws, size_t ws_size,
                              hipStream_t stream) {
    const float* x    = (const float*)d_in[0];
    const float* tiv  = (const float*)d_in[1];
    const int*   msk  = (const int*)d_in[2];
    const float* Wq   = (const float*)d_in[3];
    const float* bq   = (const float*)d_in[4];
    const float* Wk   = (const float*)d_in[5];
    const float* bk   = (const float*)d_in[6];
    const float* Wv   = (const float*)d_in[7];
    const float* bv   = (const float*)d_in[8];
    const float* alp  = (const float*)d_in[9];

    char* ws = (char*)d_ws;
    const size_t XB_OFF = 0;                                  // 16,777,216 B
    const size_t WT_OFF = XB_OFF + (size_t)MROWS * HID * 2;   // + 6,291,456 B
    const size_t Q_OFF  = WT_OFF + (size_t)3 * HID * HID * 2;
    const size_t K_OFF  = Q_OFF + (size_t)MROWS * HID * 2;
    const size_t V_OFF  = K_OFF + (size_t)MROWS * HID * 2;
    const size_t B_OFF  = V_OFF + (size_t)MROWS * HID * 2;    // biasT: 33,554,432 B

    _Float16* xb   = (_Float16*)(ws + XB_OFF);
    _Float16* wt   = (_Float16*)(ws + WT_OFF);
    _Float16* Qb   = (_Float16*)(ws + Q_OFF);
    _Float16* Kb   = (_Float16*)(ws + K_OFF);
    _Float16* Vtb  = (_Float16*)(ws + V_OFF);
    _Float16* bias = (_Float16*)(ws + B_OFF);

    cvt_x<<<MROWS * HID / (256 * 8), 256, 0, stream>>>(x, xb);
    dim3 tb(32, 8);
    transw<<<dim3(32, 32, 3), tb, 0, stream>>>(Wq, Wk, Wv, wt);
    mkbias<<<dim3(SEQ / 256, SEQ / 16, BATCH), 256, 0, stream>>>(tiv, msk, alp, bias);
    gemm_qkv<<<dim3(HID / 128, MROWS / 128, 3), 256, 0, stream>>>(
        xb, wt, bq, bk, bv, Qb, Kb, Vtb);
    attn<<<dim3(SEQ / 128, BATCH * HEADS), 256, 0, stream>>>(Qb, Kb, Vtb, bias,
                                                             (float*)d_out);
}